// Round 1
// baseline (227.440 us; speedup 1.0000x reference)
//
#include <hip/hip_runtime.h>
#include <hip/hip_bf16.h>

// OptimizedISM: D [4,256,32,32] f32, S [4,256,64,64] f32 -> Z [4,256,64,64] f32
// Z[b,c,h,w] = sum_{i,j} softmax_j(Q[b,:,h,w]·S[b,:,i,j] / 16) * S[b,c,i,j] + Q[b,c,h,w]
// where Q = nearest-upsample(D) -> only 1024 distinct queries per batch (2x2 blocks equal).

typedef __attribute__((ext_vector_type(8))) short bf16x8;
typedef __attribute__((ext_vector_type(4))) float f32x4;
typedef __attribute__((ext_vector_type(2))) float f32x2;

#define MFMA16(a, b, c) __builtin_amdgcn_mfma_f32_16x16x32_bf16(a, b, c, 0, 0, 0)

__device__ __forceinline__ unsigned short f2bf(float v) {
    union { __hip_bfloat16 h; unsigned short u; } cv;
    cv.h = __float2bfloat16(v);
    return cv.u;
}

// ---------------------------------------------------------------------------
// Prep: convert fp32 [B][256][ncols] to bf16, transposed [B][ncols][256] (outT)
// and optionally same-layout bf16 copy (outC). Tile 32x32 via LDS.
// ---------------------------------------------------------------------------
__global__ __launch_bounds__(256) void cvt_transpose(
    const float* __restrict__ in, unsigned short* __restrict__ outT,
    unsigned short* __restrict__ outC, int ncols)
{
    __shared__ float tile[32][33];
    const int bz = blockIdx.z;
    const int p0 = blockIdx.x << 5;
    const int c0 = blockIdx.y << 5;
    const int tx = threadIdx.x & 31;
    const int ty = threadIdx.x >> 5;

    const float* src = in + ((size_t)bz * 256 + c0) * ncols + p0;
#pragma unroll
    for (int k = 0; k < 4; ++k) {
        const int cc = ty + (k << 3);
        float v = src[(size_t)cc * ncols + tx];
        tile[cc][tx] = v;
        if (outC) outC[((size_t)bz * 256 + (c0 + cc)) * ncols + p0 + tx] = f2bf(v);
    }
    __syncthreads();
    unsigned short* dst = outT + ((size_t)bz * ncols + p0) * 256 + c0;
#pragma unroll
    for (int k = 0; k < 4; ++k) {
        const int pp = ty + (k << 3);
        dst[(size_t)pp * 256 + tx] = f2bf(tile[tx][pp]);
    }
}

// ---------------------------------------------------------------------------
// Main fused attention kernel.
// Grid: 256 blocks x 256 threads. Block = (batch b, 16-query tile qt).
// XCD-aware mapping: XCD x = blockIdx%8 serves batch x>>1 (4.5MB set -> L2 resident).
// 4 waves split the 64 i-groups (16 each); register Z partials; LDS reduce at end.
// ---------------------------------------------------------------------------
__global__ __launch_bounds__(256, 1) void ism_attn(
    const float* __restrict__ D,          // [4][256][32][32] f32 (residual source)
    const unsigned short* __restrict__ Kt, // [4][4096][256] bf16 (pos-major)
    const unsigned short* __restrict__ Vt, // [4][256][4096] bf16 (c-major)
    const unsigned short* __restrict__ Qb, // [4][1024][256] bf16 (q-major)
    float* __restrict__ Z)                 // [4][256][64][64] f32
{
    __shared__ unsigned short plds[4][16][72]; // per-wave P tile (pad 72: 144B rows, 16B aligned)
    __shared__ float zbuf[4][16][257];         // cross-wave reduction

    const int tid = threadIdx.x;
    const int wid = tid >> 6;
    const int lane = tid & 63;
    const int lrow = lane & 15;
    const int lgrp = lane >> 4;

    const int x = blockIdx.x & 7;
    const int b = x >> 1;
    const int qt = (x & 1) + ((blockIdx.x >> 3) << 1); // 0..63
    const int qbase = qt << 4;

    // Q fragments (A operand), held for all 16 i-iterations.
    bf16x8 aq[8];
    {
        const unsigned short* qp = Qb + ((size_t)(b * 1024 + qbase + lrow)) * 256 + lgrp * 8;
#pragma unroll
        for (int kk = 0; kk < 8; ++kk) aq[kk] = *(const bf16x8*)(qp + kk * 32);
    }

    const f32x4 fzero = {0.f, 0.f, 0.f, 0.f};
    f32x4 z[16];
#pragma unroll
    for (int ct = 0; ct < 16; ++ct) z[ct] = fzero;

    const unsigned short* ktb = Kt + (size_t)b * 4096 * 256;
    const unsigned short* vtb = Vt + (size_t)b * 256 * 4096;

    for (int it = 0; it < 16; ++it) {
        const int i = (wid << 4) + it;

        // ---- QK^T: sim[16q x 64j], K-dim = 256 channels ----
        f32x4 s[4];
#pragma unroll
        for (int jt = 0; jt < 4; ++jt) s[jt] = fzero;
        const unsigned short* kp = ktb + (size_t)(i * 64) * 256;
#pragma unroll
        for (int kk = 0; kk < 8; ++kk) {
#pragma unroll
            for (int jt = 0; jt < 4; ++jt) {
                bf16x8 bk = *(const bf16x8*)(kp + (size_t)((jt * 16 + lrow)) * 256 + kk * 32 + lgrp * 8);
                s[jt] = MFMA16(aq[kk], bk, s[jt]);
            }
        }

        // ---- softmax over j (64 values per query row) ----
        // lane holds sim[q = 4*lgrp + r][j = jt*16 + lrow]; reduce over lrow via shfl_xor.
        float mr[4], sm[4];
#pragma unroll
        for (int r = 0; r < 4; ++r) {
            float m0 = fmaxf(fmaxf(s[0][r], s[1][r]), fmaxf(s[2][r], s[3][r]));
            m0 = fmaxf(m0, __shfl_xor(m0, 1));
            m0 = fmaxf(m0, __shfl_xor(m0, 2));
            m0 = fmaxf(m0, __shfl_xor(m0, 4));
            m0 = fmaxf(m0, __shfl_xor(m0, 8));
            mr[r] = m0;
            sm[r] = 0.f;
        }
        const float SC = 0.09016844f; // log2(e) / TEMPERATURE(16)
#pragma unroll
        for (int jt = 0; jt < 4; ++jt)
#pragma unroll
            for (int r = 0; r < 4; ++r) {
                float p = exp2f((s[jt][r] - mr[r]) * SC);
                s[jt][r] = p;
                sm[r] += p;
            }
#pragma unroll
        for (int r = 0; r < 4; ++r) {
            float t = sm[r];
            t += __shfl_xor(t, 1);
            t += __shfl_xor(t, 2);
            t += __shfl_xor(t, 4);
            t += __shfl_xor(t, 8);
            sm[r] = 1.0f / t;
        }

        // ---- P -> LDS (normalized, bf16), re-read as PV A-fragments ----
#pragma unroll
        for (int jt = 0; jt < 4; ++jt)
#pragma unroll
            for (int r = 0; r < 4; ++r)
                plds[wid][(lgrp << 2) + r][(jt << 4) + lrow] = f2bf(s[jt][r] * sm[r]);
        // wave-private LDS: compiler inserts lgkmcnt wait; no barrier needed.
        bf16x8 ap0 = *(const bf16x8*)&plds[wid][lrow][lgrp * 8];
        bf16x8 ap1 = *(const bf16x8*)&plds[wid][lrow][32 + lgrp * 8];

        // ---- PV: Z[16q x 256c] += P[16x64] * V[64x256] ----
        const unsigned short* vp = vtb + i * 64 + lgrp * 8;
#pragma unroll
        for (int ct = 0; ct < 16; ++ct) {
            const unsigned short* vr = vp + (size_t)(ct * 16 + lrow) * 4096;
            bf16x8 v0 = *(const bf16x8*)(vr);
            bf16x8 v1 = *(const bf16x8*)(vr + 32);
            z[ct] = MFMA16(ap0, v0, z[ct]);
            z[ct] = MFMA16(ap1, v1, z[ct]);
        }
    }

    // ---- cross-wave reduce + residual + replicated 2x2 store ----
#pragma unroll
    for (int ct = 0; ct < 16; ++ct)
#pragma unroll
        for (int r = 0; r < 4; ++r)
            zbuf[wid][(lgrp << 2) + r][ct * 16 + lrow] = z[ct][r];
    __syncthreads();

    const int m = tid & 15;   // query within tile
    const int ch = tid >> 4;  // 0..15 channel sub-index
    const int qh = qt >> 1;
    const int qw = ((qt & 1) << 4) + m;
#pragma unroll
    for (int cc = 0; cc < 16; ++cc) {
        const int c = (cc << 4) + ch;
        float v = zbuf[0][m][c] + zbuf[1][m][c] + zbuf[2][m][c] + zbuf[3][m][c];
        v += D[(((size_t)b * 256 + c) * 32 + qh) * 32 + qw];
        f32x2 val = {v, v};
        float* op = Z + (((size_t)b * 256 + c) * 64 + (qh * 2)) * 64 + qw * 2;
        *(f32x2*)op = val;
        *(f32x2*)(op + 64) = val;
    }
}

// ---------------------------------------------------------------------------
extern "C" void kernel_launch(void* const* d_in, const int* in_sizes, int n_in,
                              void* d_out, int out_size, void* d_ws, size_t ws_size,
                              hipStream_t stream)
{
    const float* D = (const float*)d_in[0]; // [4,256,32,32]
    const float* S = (const float*)d_in[1]; // [4,256,64,64]
    float* Z = (float*)d_out;

    unsigned short* Kt = (unsigned short*)d_ws;           // [4][4096][256] bf16, 8 MB
    unsigned short* Vt = Kt + (size_t)4 * 4096 * 256;     // [4][256][4096] bf16, 8 MB
    unsigned short* Qb = Vt + (size_t)4 * 256 * 4096;     // [4][1024][256] bf16, 2 MB

    // S -> Kt (transposed) + Vt (same layout, bf16)
    cvt_transpose<<<dim3(128, 8, 4), 256, 0, stream>>>(S, Kt, Vt, 4096);
    // D -> Qb (transposed); residual is read from D directly in the main kernel
    cvt_transpose<<<dim3(32, 8, 4), 256, 0, stream>>>(D, Qb, nullptr, 1024);

    ism_attn<<<dim3(256), 256, 0, stream>>>(D, Kt, Vt, Qb, Z);
}

// Round 2
// 159.226 us; speedup vs baseline: 1.4284x; 1.4284x over previous
//
#include <hip/hip_runtime.h>
#include <hip/hip_bf16.h>

// OptimizedISM: D [4,256,32,32] f32, S [4,256,64,64] f32 -> Z [4,256,64,64] f32
// Z[b,c,h,w] = sum_{i,j} softmax_j(Q[b,:,h,w]·S[b,:,i,j] / 16) * S[b,c,i,j] + Q[b,c,h,w]
// Q = nearest-upsample(D): only 1024 distinct queries/batch (2x2 output blocks equal).

typedef __attribute__((ext_vector_type(8))) short bf16x8;
typedef __attribute__((ext_vector_type(4))) float f32x4;
typedef __attribute__((ext_vector_type(2))) float f32x2;

#define MFMA16(a, b, c) __builtin_amdgcn_mfma_f32_16x16x32_bf16(a, b, c, 0, 0, 0)

__device__ __forceinline__ unsigned short f2bf(float v) {
    union { __hip_bfloat16 h; unsigned short u; } cv;
    cv.h = __float2bfloat16(v);
    return cv.u;
}
__device__ __forceinline__ float pt_load(const float* p) { return *p; }
__device__ __forceinline__ float pt_load(const __hip_bfloat16* p) { return __bfloat162float(*p); }
__device__ __forceinline__ void pt_store(float* p, float v) { *p = v; }
__device__ __forceinline__ void pt_store(__hip_bfloat16* p, float v) { *p = __float2bfloat16(v); }

// ---------------------------------------------------------------------------
// Prep: fp32 [B][256][ncols] -> bf16 transposed [B][ncols][256] (outT)
// and optionally same-layout bf16 copy (outC).
// ---------------------------------------------------------------------------
__global__ __launch_bounds__(256) void cvt_transpose(
    const float* __restrict__ in, unsigned short* __restrict__ outT,
    unsigned short* __restrict__ outC, int ncols)
{
    __shared__ float tile[32][33];
    const int bz = blockIdx.z;
    const int p0 = blockIdx.x << 5;
    const int c0 = blockIdx.y << 5;
    const int tx = threadIdx.x & 31;
    const int ty = threadIdx.x >> 5;

    const float* src = in + ((size_t)bz * 256 + c0) * ncols + p0;
#pragma unroll
    for (int k = 0; k < 4; ++k) {
        const int cc = ty + (k << 3);
        float v = src[(size_t)cc * ncols + tx];
        tile[cc][tx] = v;
        if (outC) outC[((size_t)bz * 256 + (c0 + cc)) * ncols + p0 + tx] = f2bf(v);
    }
    __syncthreads();
    unsigned short* dst = outT + ((size_t)bz * ncols + p0) * 256 + c0;
#pragma unroll
    for (int k = 0; k < 4; ++k) {
        const int pp = ty + (k << 3);
        dst[(size_t)pp * 256 + tx] = f2bf(tile[tx][pp]);
    }
}

// ---------------------------------------------------------------------------
// Main attention kernel.
// Grid: 256 blocks x 1024 threads (16 waves -> 4 waves/SIMD at 1 block/CU).
// Block = (b, qc [128 queries], ih [8 i-groups]). Wave (t,s): tile t (16 q),
// i-half s (4 groups). In-block reduce over s; 8 cross-block partials in ws.
// XCD swizzle: xcd = blk&7 serves batch xcd>>1 -> K/V L2-resident.
// ---------------------------------------------------------------------------
template <typename PT>
__global__ __launch_bounds__(1024, 4) void ism_attn(
    const unsigned short* __restrict__ Kt,  // [4][4096][256] bf16
    const unsigned short* __restrict__ Vt,  // [4][256][4096] bf16
    const unsigned short* __restrict__ Qb,  // [4][1024][256] bf16
    PT* __restrict__ partial)               // [8ih][4b][8qc][256c][128qq]
{
    __shared__ float smem[4 * 16 * 257];    // 65792 B; also aliased as P-buffer
    unsigned short* plds = (unsigned short*)smem; // [16 waves][16][72] = 36864 B

    const int tid = threadIdx.x;
    const int wid = tid >> 6;
    const int lane = tid & 63;
    const int lrow = lane & 15;
    const int lgrp = lane >> 4;
    const int t = wid & 7;   // query tile in chunk
    const int s = wid >> 3;  // i-half

    const int blk = blockIdx.x;
    const int xcd = blk & 7;
    const int b = xcd >> 1;
    const int sub = blk >> 3;                       // 0..31
    const int qc = sub & 7;                         // 128-query chunk
    const int ih = (sub >> 3) + ((xcd & 1) << 2);   // 0..7: 8 i-groups

    const int qbase = qc * 128 + t * 16;

    // Q fragments (A operand), held across all i-iterations.
    bf16x8 aq[8];
    {
        const unsigned short* qp = Qb + ((size_t)(b * 1024 + qbase + lrow)) * 256 + lgrp * 8;
#pragma unroll
        for (int kk = 0; kk < 8; ++kk) aq[kk] = *(const bf16x8*)(qp + kk * 32);
    }

    const f32x4 fzero = {0.f, 0.f, 0.f, 0.f};
    f32x4 z[16];
#pragma unroll
    for (int ct = 0; ct < 16; ++ct) z[ct] = fzero;

    const unsigned short* ktb = Kt + (size_t)b * 4096 * 256;
    const unsigned short* vtb = Vt + (size_t)b * 256 * 4096;
    unsigned short* pl = plds + wid * (16 * 72);

    for (int g = 0; g < 4; ++g) {
        const int i = ih * 8 + s * 4 + g;

        // ---- QK^T: sim[16q x 64j] over 256 channels ----
        f32x4 sj[4];
#pragma unroll
        for (int jt = 0; jt < 4; ++jt) sj[jt] = fzero;
        const unsigned short* kp = ktb + (size_t)(i * 64) * 256;
#pragma unroll
        for (int kk = 0; kk < 8; ++kk) {
#pragma unroll
            for (int jt = 0; jt < 4; ++jt) {
                bf16x8 bk = *(const bf16x8*)(kp + (size_t)(jt * 16 + lrow) * 256 + kk * 32 + lgrp * 8);
                sj[jt] = MFMA16(aq[kk], bk, sj[jt]);
            }
        }

        // ---- softmax over j (64 per query row); lane holds [q=4lgrp+r][j=jt*16+lrow] ----
        float mr[4], sm[4];
#pragma unroll
        for (int r = 0; r < 4; ++r) {
            float m0 = fmaxf(fmaxf(sj[0][r], sj[1][r]), fmaxf(sj[2][r], sj[3][r]));
            m0 = fmaxf(m0, __shfl_xor(m0, 1));
            m0 = fmaxf(m0, __shfl_xor(m0, 2));
            m0 = fmaxf(m0, __shfl_xor(m0, 4));
            m0 = fmaxf(m0, __shfl_xor(m0, 8));
            mr[r] = m0;
            sm[r] = 0.f;
        }
        const float SC = 0.09016844f; // log2(e)/16
#pragma unroll
        for (int jt = 0; jt < 4; ++jt)
#pragma unroll
            for (int r = 0; r < 4; ++r) {
                float p = exp2f((sj[jt][r] - mr[r]) * SC);
                sj[jt][r] = p;
                sm[r] += p;
            }
#pragma unroll
        for (int r = 0; r < 4; ++r) {
            float tt = sm[r];
            tt += __shfl_xor(tt, 1);
            tt += __shfl_xor(tt, 2);
            tt += __shfl_xor(tt, 4);
            tt += __shfl_xor(tt, 8);
            sm[r] = 1.0f / tt;
        }

        // ---- P -> wave-private LDS (bf16), re-read as PV A-fragments ----
#pragma unroll
        for (int jt = 0; jt < 4; ++jt)
#pragma unroll
            for (int r = 0; r < 4; ++r)
                pl[((lgrp << 2) + r) * 72 + (jt << 4) + lrow] = f2bf(sj[jt][r] * sm[r]);
        bf16x8 ap0 = *(const bf16x8*)&pl[lrow * 72 + lgrp * 8];
        bf16x8 ap1 = *(const bf16x8*)&pl[lrow * 72 + 32 + lgrp * 8];

        // ---- PV: Z[16q x 256c] += P[16x64] * V[64x256] ----
        const unsigned short* vp = vtb + i * 64 + lgrp * 8;
#pragma unroll
        for (int ct = 0; ct < 16; ++ct) {
            const unsigned short* vr = vp + (size_t)(ct * 16 + lrow) * 4096;
            bf16x8 v0 = *(const bf16x8*)(vr);
            bf16x8 v1 = *(const bf16x8*)(vr + 32);
            z[ct] = MFMA16(ap0, v0, z[ct]);
            z[ct] = MFMA16(ap1, v1, z[ct]);
        }
    }

    // ---- epilogue: reduce s=0 + s=1 in LDS (two tile-halves), store partial ----
    __syncthreads();  // all waves done with plds region
    PT* pb = partial + ((((size_t)ih * 4 + b) * 8 + qc) * 256) * 128;

#pragma unroll 1
    for (int half = 0; half < 2; ++half) {
        const int tl = t - half * 4;  // local tile 0..3 if this wave participates
        if (s == 1 && tl >= 0 && tl < 4) {
#pragma unroll
            for (int ct = 0; ct < 16; ++ct)
#pragma unroll
                for (int r = 0; r < 4; ++r)
                    smem[(tl * 16 + (lgrp << 2) + r) * 257 + ct * 16 + lrow] = z[ct][r];
        }
        __syncthreads();
        if (s == 0 && tl >= 0 && tl < 4) {
#pragma unroll
            for (int ct = 0; ct < 16; ++ct)
#pragma unroll
                for (int r = 0; r < 4; ++r) {
                    const int idx = (tl * 16 + (lgrp << 2) + r) * 257 + ct * 16 + lrow;
                    smem[idx] += z[ct][r];
                }
        }
        __syncthreads();
        // store 64q x 256c: partial[c][half*64 + ql], coalesced; LDS pad 257 -> conflict-free
#pragma unroll
        for (int k = 0; k < 16; ++k) {
            const int l = tid + (k << 10);  // 0..16383
            const int ql = l & 63;
            const int c = l >> 6;
            pt_store(&pb[(size_t)c * 128 + half * 64 + ql], smem[ql * 257 + c]);
        }
        __syncthreads();
    }
}

// ---------------------------------------------------------------------------
// Reduce: sum 8 ih-partials + residual (exact f32 D), write 2x2-duplicated out.
// ---------------------------------------------------------------------------
template <typename PT>
__global__ __launch_bounds__(256) void ism_reduce(
    const PT* __restrict__ partial, const float* __restrict__ D, float* __restrict__ Z)
{
    const int lin = blockIdx.x * 256 + threadIdx.x;  // [b][c][q], q fastest
    const int q = lin & 1023;
    const int c = (lin >> 10) & 255;
    const int b = lin >> 18;

    float v = D[((size_t)b * 256 + c) * 1024 + q];  // D[b][c][qh][qw], offset == q
    const PT* pp = partial + (((size_t)(b * 8 + (q >> 7)) * 256 + c) * 128) + (q & 127);
#pragma unroll
    for (int ih = 0; ih < 8; ++ih)
        v += pt_load(&pp[(size_t)ih * 4 * 8 * 256 * 128]);

    const int qh = q >> 5, qw = q & 31;
    float* o = Z + (((size_t)b * 256 + c) * 64 + qh * 2) * 64 + qw * 2;
    f32x2 val = {v, v};
    *(f32x2*)o = val;
    *(f32x2*)(o + 64) = val;
}

// ---------------------------------------------------------------------------
extern "C" void kernel_launch(void* const* d_in, const int* in_sizes, int n_in,
                              void* d_out, int out_size, void* d_ws, size_t ws_size,
                              hipStream_t stream)
{
    const float* D = (const float*)d_in[0];  // [4,256,32,32]
    const float* S = (const float*)d_in[1];  // [4,256,64,64]
    float* Z = (float*)d_out;

    unsigned short* Kt = (unsigned short*)d_ws;        // 8 MB  [4][4096][256]
    unsigned short* Vt = Kt + (size_t)4 * 4096 * 256;  // 8 MB  [4][256][4096]
    unsigned short* Qb = Vt + (size_t)4 * 256 * 4096;  // 2 MB  [4][1024][256]
    char* pbase = (char*)d_ws + 18874368;              // partials after 18 MB

    cvt_transpose<<<dim3(128, 8, 4), 256, 0, stream>>>(S, Kt, Vt, 4096);
    cvt_transpose<<<dim3(32, 8, 4), 256, 0, stream>>>(D, Qb, nullptr, 1024);

    const size_t need_f32 = 18874368 + (size_t)8 * 4 * 8 * 256 * 128 * 4;  // 50 MB
    if (ws_size >= need_f32) {
        ism_attn<float><<<256, 1024, 0, stream>>>(Kt, Vt, Qb, (float*)pbase);
        ism_reduce<float><<<4096, 256, 0, stream>>>((const float*)pbase, D, Z);
    } else {
        ism_attn<__hip_bfloat16><<<256, 1024, 0, stream>>>(Kt, Vt, Qb, (__hip_bfloat16*)pbase);
        ism_reduce<__hip_bfloat16><<<4096, 256, 0, stream>>>((const __hip_bfloat16*)pbase, D, Z);
    }
}

// Round 3
// 121.346 us; speedup vs baseline: 1.8743x; 1.3122x over previous
//
#include <hip/hip_runtime.h>
#include <hip/hip_bf16.h>

// OptimizedISM: D [4,256,32,32] f32, S [4,256,64,64] f32 -> Z [4,256,64,64] f32
// Z[b,c,h,w] = sum_{i,j} softmax_j(Q[b,:,h,w]·S[b,:,i,j]/16) * S[b,c,i,j] + Q[b,c,h,w]
// Q = nearest-upsample(D): 1024 distinct queries/batch.
// Two-phase: P = softmax(Q K^T) -> ws;  Z = P V + D (K-split 4, f32 atomic acc).

typedef __attribute__((ext_vector_type(8))) short bf16x8;
typedef __attribute__((ext_vector_type(4))) float f32x4;
typedef __attribute__((ext_vector_type(2))) float f32x2;

#define MFMA16(a, b, c) __builtin_amdgcn_mfma_f32_16x16x32_bf16(a, b, c, 0, 0, 0)

__device__ __forceinline__ unsigned short f2bf(float v) {
    union { __hip_bfloat16 h; unsigned short u; } cv;
    cv.h = __float2bfloat16(v);
    return cv.u;
}

// async global->LDS, 16B per lane; dest = wave-uniform base + lane*16 (linear).
__device__ __forceinline__ void gl_lds16(const unsigned short* g, unsigned short* l) {
    __builtin_amdgcn_global_load_lds(
        (const __attribute__((address_space(1))) unsigned int*)g,
        (__attribute__((address_space(3))) unsigned int*)l, 16, 0, 0);
}

// ---------------------------------------------------------------------------
// Prep: fp32 [B][256][ncols] -> bf16 transposed [B][ncols][256] (outT)
// and optionally same-layout bf16 copy (outC).
// ---------------------------------------------------------------------------
__global__ __launch_bounds__(256) void cvt_transpose(
    const float* __restrict__ in, unsigned short* __restrict__ outT,
    unsigned short* __restrict__ outC, int ncols)
{
    __shared__ float tile[32][33];
    const int bz = blockIdx.z;
    const int p0 = blockIdx.x << 5;
    const int c0 = blockIdx.y << 5;
    const int tx = threadIdx.x & 31;
    const int ty = threadIdx.x >> 5;

    const float* src = in + ((size_t)bz * 256 + c0) * ncols + p0;
#pragma unroll
    for (int k = 0; k < 4; ++k) {
        const int cc = ty + (k << 3);
        float v = src[(size_t)cc * ncols + tx];
        tile[cc][tx] = v;
        if (outC) outC[((size_t)bz * 256 + (c0 + cc)) * ncols + p0 + tx] = f2bf(v);
    }
    __syncthreads();
    unsigned short* dst = outT + ((size_t)bz * ncols + p0) * 256 + c0;
#pragma unroll
    for (int k = 0; k < 4; ++k) {
        const int pp = ty + (k << 3);
        dst[(size_t)pp * 256 + tx] = f2bf(tile[tx][pp]);
    }
}

// ---------------------------------------------------------------------------
// Phase A: P[b][q][ij] = softmax_j(Q·K^T / 16), bf16.
// Block = (b, qt: 64 q-rows, it: one 64-j i-group). 4 waves, wave = 16q x 64j.
// K-tile [64][256] bf16 staged in LDS via global_load_lds w/ XOR-swizzled src.
// ---------------------------------------------------------------------------
__global__ __launch_bounds__(256, 4) void ism_qk(
    const unsigned short* __restrict__ Kt,  // [4][4096][256] bf16
    const unsigned short* __restrict__ Qb,  // [4][1024][256] bf16
    unsigned short* __restrict__ P)         // [4][1024][4096] bf16
{
    __shared__ unsigned short klds[64 * 256]; // 32 KB, chunk-swizzled

    const int tid = threadIdx.x;
    const int wid = tid >> 6;
    const int lane = tid & 63;
    const int lrow = lane & 15;
    const int lgrp = lane >> 4;

    const int blk = blockIdx.x;             // 4096 = 8 xcd * 512
    const int xcd = blk & 7;
    const int b = xcd >> 1;
    const int sub = blk >> 3;               // 0..511
    const int qt = sub & 15;
    const int it = (sub >> 4) | ((xcd & 1) << 5);  // 0..63

    // ---- stage K-tile (i-group it): rows j=0..63, 256 ch; src pre-swizzled ----
    {
        const unsigned short* kg = Kt + ((size_t)b * 4096 + (size_t)it * 64) * 256;
        const int r2 = lane >> 5;     // 0..1
        const int cc = lane & 31;     // 16B chunk in row
#pragma unroll
        for (int t = 0; t < 8; ++t) {
            const int row = wid * 16 + t * 2 + r2;
            const int scc = cc ^ (row & 7);
            gl_lds16(kg + (size_t)row * 256 + scc * 8, &klds[row * 256 + cc * 8]);
        }
    }

    // ---- Q fragments (issued before barrier; barrier drains both) ----
    bf16x8 aq[8];
    {
        const unsigned short* qp = Qb + ((size_t)b * 1024 + qt * 64 + wid * 16 + lrow) * 256 + lgrp * 8;
#pragma unroll
        for (int kk = 0; kk < 8; ++kk) aq[kk] = *(const bf16x8*)(qp + kk * 32);
    }
    __syncthreads();

    // ---- QK^T: sim[16q x 64j] over 256 ch, B from swizzled LDS ----
    const f32x4 fzero = {0.f, 0.f, 0.f, 0.f};
    f32x4 sj[4];
#pragma unroll
    for (int jt = 0; jt < 4; ++jt) sj[jt] = fzero;
    const int sw = lrow & 7;
#pragma unroll
    for (int kk = 0; kk < 8; ++kk) {
#pragma unroll
        for (int jt = 0; jt < 4; ++jt) {
            const int row = jt * 16 + lrow;
            bf16x8 bk = *(const bf16x8*)&klds[row * 256 + ((kk * 4 + lgrp) ^ sw) * 8];
            sj[jt] = MFMA16(aq[kk], bk, sj[jt]);
        }
    }

    // ---- softmax over j (lane holds [q=4lgrp+r][j=jt*16+lrow]) ----
    float mr[4], sm[4];
#pragma unroll
    for (int r = 0; r < 4; ++r) {
        float m0 = fmaxf(fmaxf(sj[0][r], sj[1][r]), fmaxf(sj[2][r], sj[3][r]));
        m0 = fmaxf(m0, __shfl_xor(m0, 1));
        m0 = fmaxf(m0, __shfl_xor(m0, 2));
        m0 = fmaxf(m0, __shfl_xor(m0, 4));
        m0 = fmaxf(m0, __shfl_xor(m0, 8));
        mr[r] = m0;
        sm[r] = 0.f;
    }
    const float SC = 0.09016844f; // log2(e)/16
#pragma unroll
    for (int jt = 0; jt < 4; ++jt)
#pragma unroll
        for (int r = 0; r < 4; ++r) {
            float p = exp2f((sj[jt][r] - mr[r]) * SC);
            sj[jt][r] = p;
            sm[r] += p;
        }
#pragma unroll
    for (int r = 0; r < 4; ++r) {
        float t = sm[r];
        t += __shfl_xor(t, 1);
        t += __shfl_xor(t, 2);
        t += __shfl_xor(t, 4);
        t += __shfl_xor(t, 8);
        sm[r] = 1.0f / t;
    }

    // ---- store P bf16: row q = qt*64+wid*16+4lgrp+r, col = it*64+jt*16+lrow ----
    unsigned short* pp = P + ((size_t)b * 1024 + qt * 64 + wid * 16 + (lgrp << 2)) * 4096 + (size_t)it * 64;
#pragma unroll
    for (int jt = 0; jt < 4; ++jt)
#pragma unroll
        for (int r = 0; r < 4; ++r)
            pp[(size_t)r * 4096 + jt * 16 + lrow] = f2bf(sj[jt][r] * sm[r]);
}

// ---------------------------------------------------------------------------
// Phase B: acc[b][c][q] (+=) P[q][ij] · V[c][ij], K-split 4 (f32 atomics).
// Block = (b, qt, ct, ks): tile 64q x 64c, K = 1024. Double-buffered 64-wide
// K-chunks for both operands via global_load_lds, XOR-swizzled.
// ---------------------------------------------------------------------------
__global__ __launch_bounds__(256, 4) void ism_pv(
    const unsigned short* __restrict__ P,   // [4][1024][4096] bf16
    const unsigned short* __restrict__ Vt,  // [4][256][4096] bf16
    float* __restrict__ acc)                // [4][256][1024] f32 (zeroed)
{
    __shared__ unsigned short alds[2][64 * 64]; // 2 x 8 KB
    __shared__ unsigned short blds[2][64 * 64]; // 2 x 8 KB

    const int tid = threadIdx.x;
    const int wid = tid >> 6;
    const int lane = tid & 63;
    const int lrow = lane & 15;
    const int lgrp = lane >> 4;

    const int blk = blockIdx.x;             // 1024 = 8 xcd * 128
    const int xcd = blk & 7;
    const int b = xcd >> 1;
    const int sub = blk >> 3;               // 0..127
    const int qt = sub & 15;
    const int ct = (sub >> 4) & 3;
    const int ks = (sub >> 6) | ((xcd & 1) << 1);  // 0..3

    const unsigned short* ag = P + ((size_t)b * 1024 + qt * 64) * 4096 + (size_t)ks * 1024;
    const unsigned short* bg = Vt + ((size_t)b * 256 + ct * 64) * 4096 + (size_t)ks * 1024;

    const int r8 = lane >> 3;  // 0..7
    const int c8 = lane & 7;
    const int scc = c8 ^ r8;

#define STAGE(buf, ch)                                                            \
    {                                                                             \
        _Pragma("unroll")                                                         \
        for (int t = 0; t < 2; ++t) {                                             \
            const int row = wid * 16 + t * 8 + r8;                                \
            gl_lds16(ag + (size_t)row * 4096 + (ch) * 64 + scc * 8,               \
                     &alds[buf][row * 64 + c8 * 8]);                              \
            gl_lds16(bg + (size_t)row * 4096 + (ch) * 64 + scc * 8,               \
                     &blds[buf][row * 64 + c8 * 8]);                              \
        }                                                                         \
    }

    const f32x4 fzero = {0.f, 0.f, 0.f, 0.f};
    f32x4 z[4];
#pragma unroll
    for (int cs = 0; cs < 4; ++cs) z[cs] = fzero;

    const int sw = lrow & 7;
    const int o0 = (lgrp ^ sw) * 8;
    const int o1 = ((lgrp + 4) ^ sw) * 8;

    STAGE(0, 0);
    __syncthreads();
    int cur = 0;
#pragma unroll 1
    for (int ch = 0; ch < 16; ++ch) {
        if (ch < 15) STAGE(cur ^ 1, ch + 1);
        const unsigned short* aw = &alds[cur][(wid * 16 + lrow) * 64];
        const unsigned short* bw = &blds[cur][lrow * 64];
        bf16x8 pa0 = *(const bf16x8*)(aw + o0);
        bf16x8 pa1 = *(const bf16x8*)(aw + o1);
#pragma unroll
        for (int cs = 0; cs < 4; ++cs) {
            bf16x8 bv0 = *(const bf16x8*)(bw + cs * 1024 + o0);
            bf16x8 bv1 = *(const bf16x8*)(bw + cs * 1024 + o1);
            z[cs] = MFMA16(pa0, bv0, z[cs]);
            z[cs] = MFMA16(pa1, bv1, z[cs]);
        }
        __syncthreads();
        cur ^= 1;
    }
#undef STAGE

    // ---- epilogue: lane holds z[cs][r] = Z[q=4lgrp+r][c=cs*16+lrow] ----
    float* ab = acc + ((size_t)b * 256 + ct * 64) * 1024 + qt * 64 + wid * 16 + (lgrp << 2);
#pragma unroll
    for (int cs = 0; cs < 4; ++cs)
#pragma unroll
        for (int r = 0; r < 4; ++r)
            atomicAdd(ab + (size_t)(cs * 16 + lrow) * 1024 + r, z[cs][r]);
}

// ---------------------------------------------------------------------------
// Reduce: Z = acc + D (exact f32 residual), 2x2 nearest-upsample duplication.
// ---------------------------------------------------------------------------
__global__ __launch_bounds__(256) void ism_red(
    const float* __restrict__ acc, const float* __restrict__ D, float* __restrict__ Z)
{
    const int blk = blockIdx.x;             // 8192 = 8 xcd * 1024
    const int xcd = blk & 7;
    const int b = xcd >> 1;
    const int lin = (blk >> 3) * 256 + threadIdx.x;  // 0..262143
    const int q0 = (lin & 511) << 1;
    const int c = ((lin >> 9) & 127) | ((xcd & 1) << 7);

    const size_t base = ((size_t)b * 256 + c) * 1024 + q0;
    f32x2 d = *(const f32x2*)(D + base);
    f32x2 a = *(const f32x2*)(acc + base);
    const float v0 = d[0] + a[0];
    const float v1 = d[1] + a[1];

    const int qh = q0 >> 5, qw = q0 & 31;
    float* o = Z + (((size_t)b * 256 + c) * 64 + qh * 2) * 64 + qw * 2;
    f32x4 val = {v0, v0, v1, v1};
    *(f32x4*)o = val;
    *(f32x4*)(o + 64) = val;
}

// ---------------------------------------------------------------------------
extern "C" void kernel_launch(void* const* d_in, const int* in_sizes, int n_in,
                              void* d_out, int out_size, void* d_ws, size_t ws_size,
                              hipStream_t stream)
{
    const float* D = (const float*)d_in[0];  // [4,256,32,32]
    const float* S = (const float*)d_in[1];  // [4,256,64,64]
    float* Z = (float*)d_out;

    // ws layout (50 MiB total):
    //  [0,8M)   Kt [4][4096][256] bf16   (dead after ism_qk; acc overlays it)
    //  [8,10M)  Qb [4][1024][256] bf16   (dead after ism_qk)
    //  [10,42M) P  [4][1024][4096] bf16
    //  [42,50M) Vt [4][256][4096] bf16
    //  acc = [0,4.2M) f32, memset between ism_qk and ism_pv.
    char* ws = (char*)d_ws;
    unsigned short* Kt = (unsigned short*)ws;
    unsigned short* Qb = (unsigned short*)(ws + 8388608);
    unsigned short* P  = (unsigned short*)(ws + 10485760);
    unsigned short* Vt = (unsigned short*)(ws + 44040192);
    float* acc = (float*)ws;

    cvt_transpose<<<dim3(128, 8, 4), 256, 0, stream>>>(S, Kt, Vt, 4096);
    cvt_transpose<<<dim3(32, 8, 4), 256, 0, stream>>>(D, Qb, nullptr, 1024);

    ism_qk<<<4096, 256, 0, stream>>>(Kt, Qb, P);

    hipMemsetAsync(acc, 0, (size_t)4 * 256 * 1024 * 4, stream);

    ism_pv<<<1024, 256, 0, stream>>>(P, Vt, acc);
    ism_red<<<8192, 256, 0, stream>>>(acc, D, Z);
}